// Round 18
// baseline (53.550 us; speedup 1.0000x reference)
//
#include <hip/hip_runtime.h>
#include <stdint.h>

typedef unsigned int u32;
typedef unsigned long long u64;
typedef int v4i  __attribute__((ext_vector_type(4)));
typedef int v16i __attribute__((ext_vector_type(16)));

// Binarized MLP via i8 MFMA, ±1 bytes, B direct from global (L2-resident).
// r18 = r17 with a SQUARE wave tile: 8 waves x (64 rows x 64 cols), 2x2
// frags, 4 MFMA per k-step. Halves per-CU LDS A-reads (1824->912; r17 was
// LDS-convoy-bound with 1:1 A-read:MFMA). launch_bounds(512,2) = 2 waves/EU
// -> 256-reg budget: acc 64 AGPR + deep unrolled A/B prefetch (r1-r17 all
// starved at <=64 VGPR). 8-wave barriers shrink convoy skew.
// Verbatim-proven: pack (r10/r15), MFMA asm + s_nop2 hazard (r13), expandpm
// (r14), transposed Ai8 (r17), 2-col epilogue (r14), BN order, Apre, L4 (r15).

#define NB    16384
#define DIN   784
#define HID   512
#define DOUT  10
#define MB    64          // rows per block; 256 blocks
#define THR   512         // 8 waves

// ws byte offsets (r10 layout)
#define W1OFF 0           // [25 ks][2 kh][512 col][16] i8  (409600 B)
#define W2OFF 409600      // [16][2][512][16]               (262144 B)
#define W3OFF 671744      // [16][2][512][16]
#define W4OFF 933888      // [16][2][32 col][16], col>=10 zeroed (16384 B)
#define APOFF 950272      // Apre f32[3][512] = g*(1/sqrt(v+eps)), bit-exact

// ---------------- pack: weights->±1 i8 + Apre (r15 verbatim) ----------------
__global__ void bmlp_pack(const float* __restrict__ w1, const float* __restrict__ w2,
                          const float* __restrict__ w3, const float* __restrict__ w4,
                          const float* __restrict__ g1, const float* __restrict__ v1,
                          const float* __restrict__ g2, const float* __restrict__ v2,
                          const float* __restrict__ g3, const float* __restrict__ v3,
                          char* __restrict__ ws)
{
    int tt = blockIdx.x * 256 + (int)threadIdx.x;
    const float* src; int base, K, dst16; bool zero = false;
    if (tt < 25600) {                         // W1
        int r = tt, ks = r >> 10, khh = (r >> 9) & 1, col = r & 511;
        base = ks * 32 + khh * 16; src = w1 + col * DIN; K = DIN; dst16 = r;
    } else if (tt < 41984) {                  // W2
        int r = tt - 25600, ks = r >> 10, khh = (r >> 9) & 1, col = r & 511;
        base = ks * 32 + khh * 16; src = w2 + col * HID; K = HID; dst16 = W2OFF / 16 + r;
    } else if (tt < 58368) {                  // W3
        int r = tt - 41984, ks = r >> 10, khh = (r >> 9) & 1, col = r & 511;
        base = ks * 32 + khh * 16; src = w3 + col * HID; K = HID; dst16 = W3OFF / 16 + r;
    } else if (tt < 59392) {                  // W4 (32-col padded, 10 real)
        int r = tt - 58368, ks = r >> 6, khh = (r >> 5) & 1, col = r & 31;
        base = ks * 32 + khh * 16; src = w4 + col * HID; K = HID; dst16 = W4OFF / 16 + r;
        zero = (col >= DOUT);
    } else {                                  // Apre
        int ai = tt - 59392;
        if (ai < 1536) {
            int ly = ai >> 9, c = ai & 511;
            const float* g = (ly == 0) ? g1 : (ly == 1) ? g2 : g3;
            const float* v = (ly == 0) ? v1 : (ly == 1) ? v2 : v3;
            float eps = (ly == 2) ? 512.0f : 1e-5f;   // EPS3 source bug: 512
            float A = __fmul_rn(g[c], __fdiv_rn(1.0f, __fsqrt_rn(__fadd_rn(v[c], eps))));
            ((float*)(ws + APOFF))[ai] = A;
        }
        return;
    }
    u32 d[4] = {0u, 0u, 0u, 0u};
    if (!zero) {
#pragma unroll
        for (int j = 0; j < 16; ++j) {
            int eg = base + j;
            u32 byte = 0;                     // K-pad -> 0 (kills act-pad +1 bytes)
            if (eg < K) byte = (src[eg] < 0.0f) ? 0xFFu : 0x01u;   // -1 / +1
            d[j >> 2] |= byte << ((j & 3) * 8);
        }
    }
    v4i val; val.x = (int)d[0]; val.y = (int)d[1]; val.z = (int)d[2]; val.w = (int)d[3];
    ((v4i*)ws)[dst16] = val;
}

// ---------------- fused MLP ----------------
// 16 bits -> 16 ±1 bytes (bit j -> byte j): 0x01 / 0xFF. (r14-proven)
__device__ __forceinline__ v4i expandpm(u32 sel)
{
    u32 e0 = (((sel      ) & 15u) * 0x00204081u) & 0x01010101u;
    u32 e1 = (((sel >> 4 ) & 15u) * 0x00204081u) & 0x01010101u;
    u32 e2 = (((sel >> 8 ) & 15u) * 0x00204081u) & 0x01010101u;
    u32 e3 = (((sel >> 12) & 15u) * 0x00204081u) & 0x01010101u;
    v4i r;
    r.x = (int)(0x01010101u + e0 * 254u);
    r.y = (int)(0x01010101u + e1 * 254u);
    r.z = (int)(0x01010101u + e2 * 254u);
    r.w = (int)(0x01010101u + e3 * 254u);
    return r;
}

// s_nop 2 covers VALU-write -> MFMA-read wait states around opaque inline
// asm (r12 lesson; r13-r17 proven).
__device__ __forceinline__ void mfma(v16i& a, v4i af, v4i bf)
{
    asm("s_nop 2\n\tv_mfma_i32_32x32x32_i8 %0, %1, %2, %0"
        : "+a"(a) : "v"(af), "v"(bf));
}

// Expand one act bit-word (row, bits [32w,32w+32)) into transposed Ai8
// slots 2w, 2w+1: addr = slot*1024 + row*16 (r17-proven, conflict-free).
__device__ __forceinline__ void expand_to(char* Ai8, int row, int slotBase, u32 aw)
{
    v4i lo = expandpm(aw & 0xFFFFu);
    v4i hi = expandpm(aw >> 16);
    *(v4i*)(Ai8 + slotBase * 1024 + row * 16) = lo;
    *(v4i*)(Ai8 + slotBase * 1024 + 1024 + row * 16) = hi;
}

// K-loop: 2 A-reads (transposed LDS, contiguous b128) + 2 B-loads (global,
// coalesced b128, L2-hot) + 4 MFMA per step. Wave tile 64x64.
template<int NK>
__device__ __forceinline__ void kloopL(const char* A, const char* __restrict__ Wg,
                                       int kh, int arow16, int coloff, v16i acc[2][2])
{
#pragma unroll
    for (int ks = 0; ks < NK; ++ks) {
        int s = 2 * ks + kh;
        const char* ap = A + s * 1024 + arow16;
        v4i af0 = *(const v4i*)(ap);             // rows l31
        v4i af1 = *(const v4i*)(ap + 512);       // rows l31+32
        const v4i* br = (const v4i*)Wg + (size_t)s * 512 + coloff;
        v4i bf0 = br[0], bf1 = br[32];           // cols wv*64+l31, +32
        mfma(acc[0][0], af0, bf0); mfma(acc[0][1], af0, bf1);
        mfma(acc[1][0], af1, bf0); mfma(acc[1][1], af1, bf1);
    }
}

// BN + sign -> ballot -> bit-packed acts (r14's 2-col epilogue, proven).
// C/D row for THIS lane = f*32 + (rg&3)+8*(rg>>2) + 4*(lane>>5).
__device__ __forceinline__ void epilogue(v16i acc[2][2], u32* dst,
    const float* __restrict__ b, const float* __restrict__ m,
    const float* __restrict__ be, const float* __restrict__ Ap,
    int lane, int wv)
{
    asm volatile("s_nop 7\ns_nop 7\ns_nop 7"        // MFMA->read fence
        : "+a"(acc[0][0]), "+a"(acc[0][1]), "+a"(acc[1][0]), "+a"(acc[1][1]));
    const int l31 = lane & 31;
    const int rAdd = (lane & 32) >> 3;              // +4 for hi lanes
    float pb[2], pm[2], pe[2], pA[2];
#pragma unroll
    for (int c = 0; c < 2; ++c) {
        int col = wv * 64 + c * 32 + l31;
        pb[c] = b[col]; pm[c] = m[col]; pe[c] = be[col]; pA[c] = Ap[col];
    }
#pragma unroll
    for (int f = 0; f < 2; ++f)
#pragma unroll
        for (int rg = 0; rg < 16; ++rg) {
            int rowMe = f * 32 + (rg & 3) + 8 * (rg >> 2) + rAdd;
#pragma unroll
            for (int c = 0; c < 2; ++c) {
                float xl = __fadd_rn((float)acc[f][c][rg], pb[c]);
                float y  = __fadd_rn(__fmul_rn(__fsub_rn(xl, pm[c]), pA[c]), pe[c]);
                u64 bal = __ballot(y < 0.0f);       // bit=1 <=> -1
                if (!(lane & 31))                   // lanes 0 and 32
                    dst[rowMe * 17 + (wv * 2 + c)] = (u32)(bal >> ((lane >> 5) << 5));
                acc[f][c][rg] = 0;
            }
        }
}

__global__ __launch_bounds__(THR, 2)   // 2 waves/EU -> 256-reg budget
void bmlp_direct(const float* __restrict__ x, const char* __restrict__ ws,
                 const float* __restrict__ b1, const float* __restrict__ m1, const float* __restrict__ be1,
                 const float* __restrict__ b2, const float* __restrict__ m2, const float* __restrict__ be2,
                 const float* __restrict__ b3, const float* __restrict__ m3, const float* __restrict__ be3,
                 const float* __restrict__ b4, float* __restrict__ out)
{
    __shared__ __align__(16) char Ai8[32 * 1024];   // ±1 act bytes, [slot][row][16]
    __shared__ u32 A1s[64 * 26];        // L1 act bits
    __shared__ u32 AA[64 * 17];         // L1/L3 out act bits
    __shared__ u32 AB[64 * 17];         // L2 out act bits

    const int tid = threadIdx.x, lane = tid & 63, wv = tid >> 6;   // wv 0..7
    const int l31 = lane & 31;
    const int kh16 = (lane & 32) >> 1;              // 0 / 16
    const int kh = kh16 >> 4;                       // 0 / 1
    const int arow16 = l31 * 16;                    // row byte offset in a slot
    const int row0 = blockIdx.x * MB;
    const int coloff = wv * 64 + l31;               // first B column (frag c=0)

    const float* Ap = (const float*)(ws + APOFF);

    // inline x-pack: wave wv packs rows [8wv,8wv+8) (13-wide ILP, r15-proven)
#pragma unroll 1
    for (int r = 0; r < 8; ++r) {
        const int row = wv * 8 + r;
        const float* xr = x + (size_t)(row0 + row) * DIN;
        float vx[13];
#pragma unroll
        for (int k = 0; k < 13; ++k) {
            int e = k * 64 + lane;
            vx[k] = (e < DIN) ? xr[e] : 1.0f;       // pad -> bit 0
        }
#pragma unroll
        for (int k = 0; k < 13; ++k) {
            u64 bal = __ballot(vx[k] < 0.0f);
            if (lane == 0) {
                A1s[row * 26 + 2 * k]     = (u32)bal;
                A1s[row * 26 + 2 * k + 1] = (u32)(bal >> 32);
            }
        }
    }
    __syncthreads();

    v16i acc[2][2];
#pragma unroll
    for (int f = 0; f < 2; ++f)
#pragma unroll
        for (int c = 0; c < 2; ++c)
#pragma unroll
            for (int i = 0; i < 16; ++i) acc[f][c][i] = 0;

    // ---- L1 chunk A: k-words 0..12 ----
    for (int i = tid; i < 64 * 13; i += THR) {
        int row = i & 63, w = i >> 6;
        expand_to(Ai8, row, 2 * w, A1s[row * 26 + w]);
    }
    __syncthreads();
    kloopL<13>(Ai8, ws + W1OFF, kh, arow16, coloff, acc);
    __syncthreads();
    // ---- L1 chunk B: k-words 13..24 (word 24 zero pads match zero weights)
    for (int i = tid; i < 64 * 12; i += THR) {
        int row = i & 63, w = i >> 6;
        expand_to(Ai8, row, 2 * w, A1s[row * 26 + 13 + w]);
    }
    __syncthreads();
    kloopL<12>(Ai8, ws + W1OFF + 13 * 16384, kh, arow16, coloff, acc);
    epilogue(acc, AA, b1, m1, be1, Ap, lane, wv);
    __syncthreads();

    // ---- L2 ----
    for (int i = tid; i < 64 * 16; i += THR) {
        int row = i & 63, w = i >> 6;
        expand_to(Ai8, row, 2 * w, AA[row * 17 + w]);
    }
    __syncthreads();
    kloopL<16>(Ai8, ws + W2OFF, kh, arow16, coloff, acc);
    epilogue(acc, AB, b2, m2, be2, Ap + 512, lane, wv);
    __syncthreads();

    // ---- L3 (eps=512 folded into Apre) ----
    for (int i = tid; i < 64 * 16; i += THR) {
        int row = i & 63, w = i >> 6;
        expand_to(Ai8, row, 2 * w, AB[row * 17 + w]);
    }
    __syncthreads();
    kloopL<16>(Ai8, ws + W3OFF, kh, arow16, coloff, acc);
    epilogue(acc, AA, b3, m3, be3, Ap + 1024, lane, wv);
    __syncthreads();                                 // AA complete before L4

    // ---- L4: wave 0 only; out = dot + b4 (r15 verbatim, 2 row-frags) ----
    if (wv == 0) {
#pragma unroll
        for (int ks = 0; ks < 16; ++ks) {
            u32 aw0 = AA[l31 * 17 + ks], aw1 = AA[(l31 + 32) * 17 + ks];
            v4i af0 = expandpm((aw0 >> kh16) & 0xFFFFu);
            v4i af1 = expandpm((aw1 >> kh16) & 0xFFFFu);
            v4i bf = *(const v4i*)(ws + W4OFF + (size_t)((ks * 2 + kh) * 32 + l31) * 16);
            mfma(acc[0][0], af0, bf);
            mfma(acc[1][0], af1, bf);
        }
        asm volatile("s_nop 7\ns_nop 7\ns_nop 7" : "+a"(acc[0][0]), "+a"(acc[1][0]));
        const int rAdd = (lane & 32) >> 3;
        if (l31 < DOUT) {
            float pb4 = b4[l31];
#pragma unroll
            for (int f = 0; f < 2; ++f)
#pragma unroll
                for (int rg = 0; rg < 16; ++rg) {
                    int rowE = f * 32 + (rg & 3) + 8 * (rg >> 2) + rAdd;
                    float dv = (f == 0) ? (float)acc[0][0][rg] : (float)acc[1][0][rg];
                    out[(size_t)(row0 + rowE) * DOUT + l31] = __fadd_rn(dv, pb4);
                }
        }
    }
}

extern "C" void kernel_launch(void* const* d_in, const int* in_sizes, int n_in,
                              void* d_out, int out_size, void* d_ws, size_t ws_size,
                              hipStream_t stream)
{
    const float* x   = (const float*)d_in[0];
    const float* w1  = (const float*)d_in[1];
    const float* b1  = (const float*)d_in[2];
    const float* g1  = (const float*)d_in[3];
    const float* be1 = (const float*)d_in[4];
    const float* m1  = (const float*)d_in[5];
    const float* v1  = (const float*)d_in[6];
    const float* w2  = (const float*)d_in[7];
    const float* b2  = (const float*)d_in[8];
    const float* g2  = (const float*)d_in[9];
    const float* be2 = (const float*)d_in[10];
    const float* m2  = (const float*)d_in[11];
    const float* v2  = (const float*)d_in[12];
    const float* w3  = (const float*)d_in[13];
    const float* b3  = (const float*)d_in[14];
    const float* g3  = (const float*)d_in[15];
    const float* be3 = (const float*)d_in[16];
    const float* m3  = (const float*)d_in[17];
    const float* v3  = (const float*)d_in[18];
    const float* w4  = (const float*)d_in[19];
    const float* b4  = (const float*)d_in[20];
    float* out = (float*)d_out;
    char* ws = (char*)d_ws;                 // ~956 KB used

    // weights + Apre only: 59392+1536 threads -> 238 blocks of 256
    bmlp_pack<<<dim3(238), 256, 0, stream>>>(
        w1, w2, w3, w4, g1, v1, g2, v2, g3, v3, ws);

    bmlp_direct<<<dim3(NB / MB), THR, 0, stream>>>(
        x, ws,
        b1, m1, be1,
        b2, m2, be2,
        b3, m3, be3,
        b4, out);
}

// Round 19
// 41.291 us; speedup vs baseline: 1.2969x; 1.2969x over previous
//
#include <hip/hip_runtime.h>
#include <stdint.h>

typedef unsigned int u32;
typedef unsigned long long u64;
typedef int v4i  __attribute__((ext_vector_type(4)));
typedef int v16i __attribute__((ext_vector_type(16)));

// Binarized MLP via i8 MFMA, ±1 bytes, B direct from global (L2-resident).
// r19: 2 BLOCKS PER CU (first time this session). MB=32, 512 thr (8 waves x
// 32row-x-64col tile, acc[2]=32 AGPR), LDS 24KB, launch_bounds(512,4) ->
// k = 4*4/8 = 2 blocks/CU, 128-reg budget. Cross-block phase overlap: one
// block's MFMA kloop hides the other's expand/epilogue/barriers. r18's
// regression was launch_bounds(512,2) = 1 block/CU (2nd arg is waves/EU).
// Cost accepted: B L2 traffic 2x (476MB ~ 14us, overlapped).
// Verbatim-proven: pack (r10/r15), MFMA asm + s_nop2 hazard (r13), expandpm
// (r14), transposed Ai8 (r17), 2-col epilogue (r14/r18), BN order, Apre, L4.

#define NB    16384
#define DIN   784
#define HID   512
#define DOUT  10
#define MB    32          // rows per block; 512 blocks (2/CU)
#define THR   512         // 8 waves

// ws byte offsets (r10 layout)
#define W1OFF 0           // [25 ks][2 kh][512 col][16] i8  (409600 B)
#define W2OFF 409600      // [16][2][512][16]               (262144 B)
#define W3OFF 671744      // [16][2][512][16]
#define W4OFF 933888      // [16][2][32 col][16], col>=10 zeroed (16384 B)
#define APOFF 950272      // Apre f32[3][512] = g*(1/sqrt(v+eps)), bit-exact

// ---------------- pack: weights->±1 i8 + Apre (r15 verbatim) ----------------
__global__ void bmlp_pack(const float* __restrict__ w1, const float* __restrict__ w2,
                          const float* __restrict__ w3, const float* __restrict__ w4,
                          const float* __restrict__ g1, const float* __restrict__ v1,
                          const float* __restrict__ g2, const float* __restrict__ v2,
                          const float* __restrict__ g3, const float* __restrict__ v3,
                          char* __restrict__ ws)
{
    int tt = blockIdx.x * 256 + (int)threadIdx.x;
    const float* src; int base, K, dst16; bool zero = false;
    if (tt < 25600) {                         // W1
        int r = tt, ks = r >> 10, khh = (r >> 9) & 1, col = r & 511;
        base = ks * 32 + khh * 16; src = w1 + col * DIN; K = DIN; dst16 = r;
    } else if (tt < 41984) {                  // W2
        int r = tt - 25600, ks = r >> 10, khh = (r >> 9) & 1, col = r & 511;
        base = ks * 32 + khh * 16; src = w2 + col * HID; K = HID; dst16 = W2OFF / 16 + r;
    } else if (tt < 58368) {                  // W3
        int r = tt - 41984, ks = r >> 10, khh = (r >> 9) & 1, col = r & 511;
        base = ks * 32 + khh * 16; src = w3 + col * HID; K = HID; dst16 = W3OFF / 16 + r;
    } else if (tt < 59392) {                  // W4 (32-col padded, 10 real)
        int r = tt - 58368, ks = r >> 6, khh = (r >> 5) & 1, col = r & 31;
        base = ks * 32 + khh * 16; src = w4 + col * HID; K = HID; dst16 = W4OFF / 16 + r;
        zero = (col >= DOUT);
    } else {                                  // Apre
        int ai = tt - 59392;
        if (ai < 1536) {
            int ly = ai >> 9, c = ai & 511;
            const float* g = (ly == 0) ? g1 : (ly == 1) ? g2 : g3;
            const float* v = (ly == 0) ? v1 : (ly == 1) ? v2 : v3;
            float eps = (ly == 2) ? 512.0f : 1e-5f;   // EPS3 source bug: 512
            float A = __fmul_rn(g[c], __fdiv_rn(1.0f, __fsqrt_rn(__fadd_rn(v[c], eps))));
            ((float*)(ws + APOFF))[ai] = A;
        }
        return;
    }
    u32 d[4] = {0u, 0u, 0u, 0u};
    if (!zero) {
#pragma unroll
        for (int j = 0; j < 16; ++j) {
            int eg = base + j;
            u32 byte = 0;                     // K-pad -> 0 (kills act-pad +1 bytes)
            if (eg < K) byte = (src[eg] < 0.0f) ? 0xFFu : 0x01u;   // -1 / +1
            d[j >> 2] |= byte << ((j & 3) * 8);
        }
    }
    v4i val; val.x = (int)d[0]; val.y = (int)d[1]; val.z = (int)d[2]; val.w = (int)d[3];
    ((v4i*)ws)[dst16] = val;
}

// ---------------- fused MLP ----------------
// 16 bits -> 16 ±1 bytes (bit j -> byte j): 0x01 / 0xFF. (r14-proven)
__device__ __forceinline__ v4i expandpm(u32 sel)
{
    u32 e0 = (((sel      ) & 15u) * 0x00204081u) & 0x01010101u;
    u32 e1 = (((sel >> 4 ) & 15u) * 0x00204081u) & 0x01010101u;
    u32 e2 = (((sel >> 8 ) & 15u) * 0x00204081u) & 0x01010101u;
    u32 e3 = (((sel >> 12) & 15u) * 0x00204081u) & 0x01010101u;
    v4i r;
    r.x = (int)(0x01010101u + e0 * 254u);
    r.y = (int)(0x01010101u + e1 * 254u);
    r.z = (int)(0x01010101u + e2 * 254u);
    r.w = (int)(0x01010101u + e3 * 254u);
    return r;
}

// s_nop 2 covers VALU-write -> MFMA-read wait states around opaque inline
// asm (r12 lesson; r13-r18 proven).
__device__ __forceinline__ void mfma(v16i& a, v4i af, v4i bf)
{
    asm("s_nop 2\n\tv_mfma_i32_32x32x32_i8 %0, %1, %2, %0"
        : "+a"(a) : "v"(af), "v"(bf));
}

// Expand one act bit-word (row, bits [32w,32w+32)) into transposed Ai8
// slots 2w, 2w+1: addr = slot*512 + row*16 (32 rows/slot; r17-proven
// conflict-free pattern, halved slot size).
__device__ __forceinline__ void expand_to(char* Ai8, int row, int slotBase, u32 aw)
{
    v4i lo = expandpm(aw & 0xFFFFu);
    v4i hi = expandpm(aw >> 16);
    *(v4i*)(Ai8 + slotBase * 512 + row * 16) = lo;
    *(v4i*)(Ai8 + slotBase * 512 + 512 + row * 16) = hi;
}

// K-loop: 1 A-read (transposed LDS, contiguous b128) + 2 B-loads (global,
// coalesced b128, L2-hot) + 2 MFMA per step. Wave tile 32x64.
template<int NK>
__device__ __forceinline__ void kloopL(const char* A, const char* __restrict__ Wg,
                                       int kh, int arow16, int coloff, v16i acc[2])
{
#pragma unroll
    for (int ks = 0; ks < NK; ++ks) {
        int s = 2 * ks + kh;
        v4i af = *(const v4i*)(A + s * 512 + arow16);    // rows l31, k-half kh
        const v4i* br = (const v4i*)Wg + (size_t)s * 512 + coloff;
        v4i bf0 = br[0], bf1 = br[32];                   // cols wv*64+l31, +32
        mfma(acc[0], af, bf0);
        mfma(acc[1], af, bf1);
    }
}

// BN + sign -> ballot -> bit-packed acts (r14/r18 2-col epilogue, proven;
// single 32-row frag). C/D row for THIS lane = (rg&3)+8*(rg>>2)+4*(lane>>5).
__device__ __forceinline__ void epilogue(v16i acc[2], u32* dst,
    const float* __restrict__ b, const float* __restrict__ m,
    const float* __restrict__ be, const float* __restrict__ Ap,
    int lane, int wv)
{
    asm volatile("s_nop 7\ns_nop 7\ns_nop 7"        // MFMA->read fence
        : "+a"(acc[0]), "+a"(acc[1]));
    const int l31 = lane & 31;
    const int rAdd = (lane & 32) >> 3;              // +4 for hi lanes
    float pb[2], pm[2], pe[2], pA[2];
#pragma unroll
    for (int c = 0; c < 2; ++c) {
        int col = wv * 64 + c * 32 + l31;
        pb[c] = b[col]; pm[c] = m[col]; pe[c] = be[col]; pA[c] = Ap[col];
    }
#pragma unroll
    for (int rg = 0; rg < 16; ++rg) {
        int rowMe = (rg & 3) + 8 * (rg >> 2) + rAdd;    // 0..31
#pragma unroll
        for (int c = 0; c < 2; ++c) {
            float xl = __fadd_rn((float)acc[c][rg], pb[c]);
            float y  = __fadd_rn(__fmul_rn(__fsub_rn(xl, pm[c]), pA[c]), pe[c]);
            u64 bal = __ballot(y < 0.0f);           // bit=1 <=> -1
            if (!(lane & 31))                       // lanes 0 and 32
                dst[rowMe * 17 + (wv * 2 + c)] = (u32)(bal >> ((lane >> 5) << 5));
            acc[c][rg] = 0;
        }
    }
}

__global__ __launch_bounds__(THR, 4)   // 4 waves/EU => 2 blocks/CU, 128-reg budget
void bmlp_direct(const float* __restrict__ x, const char* __restrict__ ws,
                 const float* __restrict__ b1, const float* __restrict__ m1, const float* __restrict__ be1,
                 const float* __restrict__ b2, const float* __restrict__ m2, const float* __restrict__ be2,
                 const float* __restrict__ b3, const float* __restrict__ m3, const float* __restrict__ be3,
                 const float* __restrict__ b4, float* __restrict__ out)
{
    __shared__ __align__(16) char Ai8[32 * 512];    // ±1 act bytes, [slot][32 rows][16]
    __shared__ u32 A1s[32 * 26];        // L1 act bits
    __shared__ u32 AA[32 * 17];         // L1/L3 out act bits
    __shared__ u32 AB[32 * 17];         // L2 out act bits  => 24 KB total

    const int tid = threadIdx.x, lane = tid & 63, wv = tid >> 6;   // wv 0..7
    const int l31 = lane & 31;
    const int kh16 = (lane & 32) >> 1;              // 0 / 16
    const int kh = kh16 >> 4;                       // 0 / 1
    const int arow16 = l31 * 16;                    // row byte offset in a slot
    const int row0 = blockIdx.x * MB;
    const int coloff = wv * 64 + l31;               // first B column (frag c=0)

    const float* Ap = (const float*)(ws + APOFF);

    // inline x-pack: wave wv packs rows [4wv,4wv+4) (13-wide ILP, r15-proven)
#pragma unroll 1
    for (int r = 0; r < 4; ++r) {
        const int row = wv * 4 + r;
        const float* xr = x + (size_t)(row0 + row) * DIN;
        float vx[13];
#pragma unroll
        for (int k = 0; k < 13; ++k) {
            int e = k * 64 + lane;
            vx[k] = (e < DIN) ? xr[e] : 1.0f;       // pad -> bit 0
        }
#pragma unroll
        for (int k = 0; k < 13; ++k) {
            u64 bal = __ballot(vx[k] < 0.0f);
            if (lane == 0) {
                A1s[row * 26 + 2 * k]     = (u32)bal;
                A1s[row * 26 + 2 * k + 1] = (u32)(bal >> 32);
            }
        }
    }
    __syncthreads();

    v16i acc[2];
#pragma unroll
    for (int c = 0; c < 2; ++c)
#pragma unroll
        for (int i = 0; i < 16; ++i) acc[c][i] = 0;

    // ---- L1 chunk A: k-words 0..12 (416 expand tasks) ----
    if (tid < 32 * 13) {
        int row = tid & 31, w = tid >> 5;
        expand_to(Ai8, row, 2 * w, A1s[row * 26 + w]);
    }
    __syncthreads();
    kloopL<13>(Ai8, ws + W1OFF, kh, arow16, coloff, acc);
    __syncthreads();
    // ---- L1 chunk B: k-words 13..24 (word 24 zero pads match zero weights)
    if (tid < 32 * 12) {
        int row = tid & 31, w = tid >> 5;
        expand_to(Ai8, row, 2 * w, A1s[row * 26 + 13 + w]);
    }
    __syncthreads();
    kloopL<12>(Ai8, ws + W1OFF + 13 * 16384, kh, arow16, coloff, acc);
    epilogue(acc, AA, b1, m1, be1, Ap, lane, wv);
    __syncthreads();

    // ---- L2 (16 slices -> 32 slots exactly) ----
    {
        int row = tid & 31, w = tid >> 5;           // w 0..15
        expand_to(Ai8, row, 2 * w, AA[row * 17 + w]);
    }
    __syncthreads();
    kloopL<16>(Ai8, ws + W2OFF, kh, arow16, coloff, acc);
    epilogue(acc, AB, b2, m2, be2, Ap + 512, lane, wv);
    __syncthreads();

    // ---- L3 (eps=512 folded into Apre) ----
    {
        int row = tid & 31, w = tid >> 5;
        expand_to(Ai8, row, 2 * w, AB[row * 17 + w]);
    }
    __syncthreads();
    kloopL<16>(Ai8, ws + W3OFF, kh, arow16, coloff, acc);
    epilogue(acc, AA, b3, m3, be3, Ap + 1024, lane, wv);
    __syncthreads();                                 // AA complete before L4

    // ---- L4: wave 0 only; out = dot + b4 (r15 pattern, 1 row-frag) ----
    if (wv == 0) {
#pragma unroll
        for (int ks = 0; ks < 16; ++ks) {
            u32 aw = AA[l31 * 17 + ks];
            v4i af = expandpm((aw >> kh16) & 0xFFFFu);
            v4i bf = *(const v4i*)(ws + W4OFF + (size_t)((ks * 2 + kh) * 32 + l31) * 16);
            mfma(acc[0], af, bf);
        }
        asm volatile("s_nop 7\ns_nop 7\ns_nop 7" : "+a"(acc[0]));
        const int rAdd = (lane & 32) >> 3;
        if (l31 < DOUT) {
            float pb4 = b4[l31];
#pragma unroll
            for (int rg = 0; rg < 16; ++rg) {
                int rowE = (rg & 3) + 8 * (rg >> 2) + rAdd;     // 0..31
                out[(size_t)(row0 + rowE) * DOUT + l31] =
                    __fadd_rn((float)acc[0][rg], pb4);
            }
        }
    }
}

extern "C" void kernel_launch(void* const* d_in, const int* in_sizes, int n_in,
                              void* d_out, int out_size, void* d_ws, size_t ws_size,
                              hipStream_t stream)
{
    const float* x   = (const float*)d_in[0];
    const float* w1  = (const float*)d_in[1];
    const float* b1  = (const float*)d_in[2];
    const float* g1  = (const float*)d_in[3];
    const float* be1 = (const float*)d_in[4];
    const float* m1  = (const float*)d_in[5];
    const float* v1  = (const float*)d_in[6];
    const float* w2  = (const float*)d_in[7];
    const float* b2  = (const float*)d_in[8];
    const float* g2  = (const float*)d_in[9];
    const float* be2 = (const float*)d_in[10];
    const float* m2  = (const float*)d_in[11];
    const float* v2  = (const float*)d_in[12];
    const float* w3  = (const float*)d_in[13];
    const float* b3  = (const float*)d_in[14];
    const float* g3  = (const float*)d_in[15];
    const float* be3 = (const float*)d_in[16];
    const float* m3  = (const float*)d_in[17];
    const float* v3  = (const float*)d_in[18];
    const float* w4  = (const float*)d_in[19];
    const float* b4  = (const float*)d_in[20];
    float* out = (float*)d_out;
    char* ws = (char*)d_ws;                 // ~956 KB used

    // weights + Apre only: 59392+1536 threads -> 238 blocks of 256
    bmlp_pack<<<dim3(238), 256, 0, stream>>>(
        w1, w2, w3, w4, g1, v1, g2, v2, g3, v3, ws);

    bmlp_direct<<<dim3(NB / MB), THR, 0, stream>>>(
        x, ws,
        b1, m1, be1,
        b2, m2, be2,
        b3, m3, be3,
        b4, out);
}